// Round 9
// baseline (291.710 us; speedup 1.0000x reference)
//
#include <hip/hip_runtime.h>
#include <hip/hip_bf16.h>
#include <stdint.h>

typedef unsigned short u16;
typedef __bf16 bf16x8 __attribute__((ext_vector_type(8)));
typedef float f32x4 __attribute__((ext_vector_type(4)));
typedef unsigned int u32x4 __attribute__((ext_vector_type(4)));
typedef unsigned int u32x2 __attribute__((ext_vector_type(2)));

#define S_LEN 2048
#define DMODEL 1024
#define NHEAD 16
#define DHEAD 64
#define MROWS 4096  // B*S

__device__ __forceinline__ float b2f(u16 u) {
  union { unsigned int i; float f; } c;
  c.i = ((unsigned int)u) << 16;
  return c.f;
}
__device__ __forceinline__ u16 f2b(float f) {
  __hip_bfloat16 h = __float2bfloat16(f);
  union { __hip_bfloat16 h; u16 u; } c;
  c.h = h;
  return c.u;
}
__device__ __forceinline__ unsigned int pk2(float lo, float hi) {
  return (unsigned int)f2b(lo) | ((unsigned int)f2b(hi) << 16);
}

// async global->LDS, 16B per lane: LDS dest = wave-uniform base + lane*16.
__device__ __forceinline__ void gload16(const void* g, void* l) {
  __builtin_amdgcn_global_load_lds(
      (const __attribute__((address_space(1))) unsigned int*)(uintptr_t)g,
      (__attribute__((address_space(3))) unsigned int*)(uintptr_t)l,
      16, 0, 0);
}

// ------------- prep: fused activation cvt (z 0..2) + weight transpose (z 3..6)
__global__ __launch_bounds__(256) void prep(
    const float* __restrict__ q, const float* __restrict__ k, const float* __restrict__ v,
    const float* __restrict__ Wq, const float* __restrict__ Wk,
    const float* __restrict__ Wv, const float* __restrict__ Wo,
    u16* __restrict__ Qx, u16* __restrict__ Kx, u16* __restrict__ Vx,
    u16* __restrict__ Wqt, u16* __restrict__ Wkt,
    u16* __restrict__ Wvt, u16* __restrict__ Wot) {
  __shared__ u16 tile[64][65];
  const int z = blockIdx.z;
  const int tid = threadIdx.x;
  if (z < 3) {
    const float* src = (z == 0) ? q : (z == 1) ? k : v;
    u16* dst = (z == 0) ? Qx : (z == 1) ? Kx : Vx;
    const size_t i8 = ((size_t)blockIdx.x * 256 + tid) * 8;
    float4 a = *(const float4*)(src + i8);
    float4 b = *(const float4*)(src + i8 + 4);
    u16 o[8];
    o[0] = f2b(a.x); o[1] = f2b(a.y); o[2] = f2b(a.z); o[3] = f2b(a.w);
    o[4] = f2b(b.x); o[5] = f2b(b.y); o[6] = f2b(b.z); o[7] = f2b(b.w);
    *(u32x4*)(dst + i8) = *(const u32x4*)o;
    return;
  }
  if (blockIdx.x >= 256) return;
  const int zz = z - 3;
  const float* W = (zz == 0) ? Wq : (zz == 1) ? Wk : (zz == 2) ? Wv : Wo;
  u16* Wt = (zz == 0) ? Wqt : (zz == 1) ? Wkt : (zz == 2) ? Wvt : Wot;
  const int n0 = (blockIdx.x & 15) * 64, k0 = (blockIdx.x >> 4) * 64;
#pragma unroll
  for (int j = 0; j < 16; j++) {
    int idx = j * 256 + tid;
    int r = idx >> 6, c = idx & 63;
    tile[r][c] = f2b(W[(size_t)(k0 + r) * DMODEL + n0 + c]);
  }
  __syncthreads();
#pragma unroll
  for (int j = 0; j < 16; j++) {
    int idx = j * 256 + tid;
    int r = idx >> 6, c = idx & 63;
    Wt[(size_t)(n0 + r) * DMODEL + k0 + c] = tile[c][r];
  }
}

// ---------------- GEMM: C[M,1024] = A(bf16) * Bt(bf16)^T + bias(f32)
// m97 structure: 128x128 tile, BK=32, global_load_lds w=16, 16x16x32 bf16 MFMA.
// MODE: 0 = bf16 row-major C; 2 = bf16 transposed V-out
//       (Vt[(b*1024 + col)][s], s = row & 2047, b = row >> 11)
template <int MODE>
__device__ __forceinline__ void gemm_body(const u16* __restrict__ A,
                                          const u16* __restrict__ Bt,
                                          const float* __restrict__ bias,
                                          void* __restrict__ Cv) {
  constexpr int K = DMODEL;
  __shared__ u16 As[128 * 32];
  __shared__ u16 Bs[128 * 32];
  const int tid = threadIdx.x;
  const int wave = tid >> 6, lane = tid & 63;
  const int quad = lane >> 4, l15 = lane & 15;
  const int wr = wave >> 1, wc = wave & 1;
  const int brow = blockIdx.y, bcol = blockIdx.x;

  f32x4 acc[4][4] = {};

  for (int k0 = 0; k0 < K; k0 += 32) {
    __syncthreads();   // previous iteration's LDS reads complete
#pragma unroll
    for (int t = 0; t < 2; t++) {
      const int slot = t * 256 + wave * 64 + lane;   // 512 slots of 16B
      const int row = slot >> 2;                     // [128][32] tile
      const int col = (slot & 3) << 3;
      const int ldsb = (t * 256 + wave * 64) * 8;    // u16 units, wave-uniform
      gload16(A + (size_t)(brow * 128 + row) * K + k0 + col, As + ldsb);
      gload16(Bt + (size_t)(bcol * 128 + row) * K + k0 + col, Bs + ldsb);
    }
    __syncthreads();   // drains vmcnt (global_load_lds) + lgkm

    bf16x8 af[4], bfm[4];
#pragma unroll
    for (int i = 0; i < 4; i++)
      af[i] = *(const bf16x8*)(As + (wr * 64 + i * 16 + l15) * 32 + quad * 8);
#pragma unroll
    for (int j = 0; j < 4; j++)
      bfm[j] = *(const bf16x8*)(Bs + (wc * 64 + j * 16 + l15) * 32 + quad * 8);
#pragma unroll
    for (int i = 0; i < 4; i++)
#pragma unroll
      for (int j = 0; j < 4; j++)
        acc[i][j] = __builtin_amdgcn_mfma_f32_16x16x32_bf16(af[i], bfm[j], acc[i][j], 0, 0, 0);
  }

#pragma unroll
  for (int i = 0; i < 4; i++)
#pragma unroll
    for (int j = 0; j < 4; j++) {
      const int col = bcol * 128 + wc * 64 + j * 16 + l15;
      const float bv = bias[col];
      if (MODE == 2) {
        const int srow = brow * 128 + wr * 64 + i * 16 + quad * 4;
        const int bb = srow >> 11, s = srow & (S_LEN - 1);
        u32x2 pd;
        pd.x = pk2(acc[i][j][0] + bv, acc[i][j][1] + bv);
        pd.y = pk2(acc[i][j][2] + bv, acc[i][j][3] + bv);
        *(u32x2*)((u16*)Cv + ((size_t)(bb * 1024 + col)) * S_LEN + s) = pd;
      } else {
#pragma unroll
        for (int r = 0; r < 4; r++) {
          const int row = brow * 128 + wr * 64 + i * 16 + quad * 4 + r;
          ((u16*)Cv)[(size_t)row * DMODEL + col] = f2b(acc[i][j][r] + bv);
        }
      }
    }
}

__global__ __launch_bounds__(256) void gemm_qkv(
    const u16* __restrict__ Qx, const u16* __restrict__ Kx, const u16* __restrict__ Vx,
    const u16* __restrict__ Wqt, const u16* __restrict__ Wkt, const u16* __restrict__ Wvt,
    const float* __restrict__ bq, const float* __restrict__ bk, const float* __restrict__ bv,
    u16* __restrict__ Qp, u16* __restrict__ Kp, u16* __restrict__ Vt) {
  const int z = blockIdx.z;
  if (z == 2) {
    gemm_body<2>(Vx, Wvt, bv, Vt);
  } else {
    const u16* A = (z == 0) ? Qx : Kx;
    const u16* Bt = (z == 0) ? Wqt : Wkt;
    const float* bias = (z == 0) ? bq : bk;
    u16* C = (z == 0) ? Qp : Kp;
    gemm_body<0>(A, Bt, bias, C);
  }
}

// ---- gemm_out: 64x128 tile (512 blocks = 2/CU, vs 1/CU at 128x128), f32 out
__global__ __launch_bounds__(256) void gemm_out(
    const u16* __restrict__ A, const u16* __restrict__ Bt,
    const float* __restrict__ bias, float* __restrict__ C) {
  constexpr int K = DMODEL;
  __shared__ u16 As[64 * 32];
  __shared__ u16 Bs[128 * 32];
  const int tid = threadIdx.x;
  const int wave = tid >> 6, lane = tid & 63;
  const int quad = lane >> 4, l15 = lane & 15;
  const int wr = wave >> 1, wc = wave & 1;
  const int brow = blockIdx.y, bcol = blockIdx.x;

  f32x4 acc[2][4] = {};

  for (int k0 = 0; k0 < K; k0 += 32) {
    __syncthreads();
    {
      const int slot = wave * 64 + lane;             // 256 slots = 64x32 tile
      const int row = slot >> 2;
      const int col = (slot & 3) << 3;
      gload16(A + (size_t)(brow * 64 + row) * K + k0 + col, As + wave * 512);
    }
#pragma unroll
    for (int t = 0; t < 2; t++) {
      const int slot = t * 256 + wave * 64 + lane;   // 512 slots = 128x32 tile
      const int row = slot >> 2;
      const int col = (slot & 3) << 3;
      gload16(Bt + (size_t)(bcol * 128 + row) * K + k0 + col,
              Bs + (t * 256 + wave * 64) * 8);
    }
    __syncthreads();

    bf16x8 af[2], bfm[4];
#pragma unroll
    for (int i = 0; i < 2; i++)
      af[i] = *(const bf16x8*)(As + (wr * 32 + i * 16 + l15) * 32 + quad * 8);
#pragma unroll
    for (int j = 0; j < 4; j++)
      bfm[j] = *(const bf16x8*)(Bs + (wc * 64 + j * 16 + l15) * 32 + quad * 8);
#pragma unroll
    for (int i = 0; i < 2; i++)
#pragma unroll
      for (int j = 0; j < 4; j++)
        acc[i][j] = __builtin_amdgcn_mfma_f32_16x16x32_bf16(af[i], bfm[j], acc[i][j], 0, 0, 0);
  }

#pragma unroll
  for (int i = 0; i < 2; i++)
#pragma unroll
    for (int j = 0; j < 4; j++) {
      const int col = bcol * 128 + wc * 64 + j * 16 + l15;
      const float bv = bias[col];
#pragma unroll
      for (int r = 0; r < 4; r++) {
        const int row = brow * 64 + wr * 32 + i * 16 + quad * 4 + r;
        C[(size_t)row * DMODEL + col] = acc[i][j][r] + bv;
      }
    }
}

// ---------------- flash attention v4: direct-register K/V + per-iter barrier
// 1D grid 512, XCD-swizzled: all 16 q-tile blocks of one (b,h) on one XCD.
// LDS = Ps only (18 KB). K double-buffered in regs, prefetch mid-iteration so
// the barrier's vmcnt drain is cheap; V loaded post-barrier (hidden by S^T+exp).
// Scale folded into Q: P = exp2(S'), Q' = Q * 0.125*log2(e).
#define EXP2SCALE 0.180336880112f  // 0.125 * log2(e)
__global__ __launch_bounds__(256) void attn(const u16* __restrict__ Qp,
                                            const u16* __restrict__ Kp,
                                            const u16* __restrict__ Vt,
                                            u16* __restrict__ Op) {
  __shared__ u16 Ps[128 * 72];   // P[query][key] per-wave 32-row regions

  const int tid = threadIdx.x;
  const int wave = tid >> 6, lane = tid & 63;
  const int quad = lane >> 4, l15 = lane & 15;
  // XCD swizzle: i%8 = XCD (round-robin dispatch); give each XCD 4 (b,h) pairs
  const int i = blockIdx.x;
  const int bh = (i & 7) + 8 * (i >> 7);       // 0..31
  const int qt = (i >> 3) & 15;
  const int b = bh >> 4, h = bh & 15, s0 = qt * 128;

  const u16* Kb = Kp + ((size_t)(b * S_LEN)) * DMODEL + h * DHEAD;
  const u16* Vb = Vt + ((size_t)(b * 1024 + h * DHEAD)) * S_LEN;

  // ones B-fragment (col 0 only): lanes l15==0 hold 1.0
  bf16x8 b1;
  {
    union { u16 a[8]; bf16x8 v; } c;
    u16 one = (l15 == 0) ? 0x3F80 : 0;
#pragma unroll
    for (int j = 0; j < 8; j++) c.a[j] = one;
    b1 = c.v;
  }

  // Q fragments (B-operand of S^T), pre-scaled by 0.125*log2(e)
  bf16x8 qf[2][2];
#pragma unroll
  for (int rb = 0; rb < 2; rb++)
#pragma unroll
    for (int kx = 0; kx < 2; kx++) {
      union { u16 a[8]; bf16x8 v; u32x4 d; } c;
      c.d = *(const u32x4*)(Qp +
          ((size_t)(b * S_LEN + s0 + wave * 32 + rb * 16 + l15)) * DMODEL +
          h * DHEAD + kx * 32 + quad * 8);
#pragma unroll
      for (int j = 0; j < 8; j++) c.a[j] = f2b(b2f(c.a[j]) * EXP2SCALE);
      qf[rb][kx] = c.v;
    }

  // K fragments double-buffered in regs; preload kt=0
  bf16x8 kf[2][8];
#pragma unroll
  for (int f = 0; f < 8; f++) {
    const int n = f >> 1, kx = f & 1;
    kf[0][f] = *(const bf16x8*)(Kb + (size_t)(n * 16 + l15) * DMODEL + kx * 32 + quad * 8);
  }

  f32x4 oacc[2][4] = {};
  f32x4 lacc[2] = {};

#pragma unroll 2
  for (int kt = 0; kt < 32; kt++) {
    const int cur = kt & 1, nxt = cur ^ 1;
    __syncthreads();   // wave align + fence; drains prev-iter prefetch (cheap)

    // V for this iter — consumed after S^T+exp, latency hidden
    bf16x8 vf[8];
#pragma unroll
    for (int f = 0; f < 8; f++) {
      const int n = f >> 1, kx = f & 1;
      vf[f] = *(const bf16x8*)(Vb +
          (size_t)(n * 16 + l15) * S_LEN + kt * 64 + kx * 32 + quad * 8);
    }

    // S^T = K Q'^T: lane holds S[query=l15][key = n*16 + quad*4 + r]
    f32x4 sfT[2][4] = {};
#pragma unroll
    for (int n = 0; n < 4; n++)
#pragma unroll
      for (int kx = 0; kx < 2; kx++) {
        bf16x8 ka = kf[cur][n * 2 + kx];
        sfT[0][n] = __builtin_amdgcn_mfma_f32_16x16x32_bf16(ka, qf[0][kx], sfT[0][n], 0, 0, 0);
        sfT[1][n] = __builtin_amdgcn_mfma_f32_16x16x32_bf16(ka, qf[1][kx], sfT[1][n], 0, 0, 0);
      }

    // p = exp2(s'); pack 4 consecutive keys -> b64 store (per-wave region)
#pragma unroll
    for (int rb = 0; rb < 2; rb++)
#pragma unroll
      for (int n = 0; n < 4; n++) {
        u32x2 pd;
        pd.x = pk2(__builtin_amdgcn_exp2f(sfT[rb][n][0]),
                   __builtin_amdgcn_exp2f(sfT[rb][n][1]));
        pd.y = pk2(__builtin_amdgcn_exp2f(sfT[rb][n][2]),
                   __builtin_amdgcn_exp2f(sfT[rb][n][3]));
        *(u32x2*)(Ps + (wave * 32 + rb * 16 + l15) * 72 + n * 16 + quad * 4) = pd;
      }

    // prefetch next K tile (mid-iteration: ~full PV phase to complete)
    if (kt < 31) {
#pragma unroll
      for (int f = 0; f < 8; f++) {
        const int n = f >> 1, kx = f & 1;
        kf[nxt][f] = *(const bf16x8*)(Kb +
            (size_t)((kt + 1) * 64 + n * 16 + l15) * DMODEL + kx * 32 + quad * 8);
      }
    }

    // O += P V ; l += P * ones
#pragma unroll
    for (int kx = 0; kx < 2; kx++) {
      bf16x8 ap0 = *(const bf16x8*)(Ps + (wave * 32 + l15) * 72 + kx * 32 + quad * 8);
      bf16x8 ap1 = *(const bf16x8*)(Ps + (wave * 32 + 16 + l15) * 72 + kx * 32 + quad * 8);
      lacc[0] = __builtin_amdgcn_mfma_f32_16x16x32_bf16(ap0, b1, lacc[0], 0, 0, 0);
      lacc[1] = __builtin_amdgcn_mfma_f32_16x16x32_bf16(ap1, b1, lacc[1], 0, 0, 0);
#pragma unroll
      for (int n = 0; n < 4; n++) {
        oacc[0][n] = __builtin_amdgcn_mfma_f32_16x16x32_bf16(ap0, vf[n * 2 + kx], oacc[0][n], 0, 0, 0);
        oacc[1][n] = __builtin_amdgcn_mfma_f32_16x16x32_bf16(ap1, vf[n * 2 + kx], oacc[1][n], 0, 0, 0);
      }
    }
  }

  // epilogue: l lives in lanes l15==0 (col 0) — broadcast within quad, divide
#pragma unroll
  for (int rb = 0; rb < 2; rb++) {
    float inv[4];
#pragma unroll
    for (int r = 0; r < 4; r++)
      inv[r] = 1.0f / __shfl(lacc[rb][r], quad * 16);
#pragma unroll
    for (int n = 0; n < 4; n++)
#pragma unroll
      for (int r = 0; r < 4; r++) {
        int row = s0 + wave * 32 + rb * 16 + quad * 4 + r;
        int col = h * DHEAD + n * 16 + l15;
        Op[((size_t)(b * S_LEN + row)) * DMODEL + col] = f2b(oacc[rb][n][r] * inv[r]);
      }
  }
}

extern "C" void kernel_launch(void* const* d_in, const int* in_sizes, int n_in,
                              void* d_out, int out_size, void* d_ws, size_t ws_size,
                              hipStream_t stream) {
  const float* q  = (const float*)d_in[0];
  const float* k  = (const float*)d_in[1];
  const float* v  = (const float*)d_in[2];
  const float* Wq = (const float*)d_in[3];
  const float* bq = (const float*)d_in[4];
  const float* Wk = (const float*)d_in[5];
  const float* bk = (const float*)d_in[6];
  const float* Wv = (const float*)d_in[7];
  const float* bv = (const float*)d_in[8];
  const float* Wo = (const float*)d_in[9];
  const float* bo = (const float*)d_in[10];

  char* w = (char*)d_ws;
  const size_t WSZ = (size_t)DMODEL * DMODEL * 2;  // 2 MB per transposed weight
  const size_t XSZ = (size_t)MROWS * DMODEL * 2;   // 8 MB per bf16 activation
  u16* Wqt = (u16*)(w);
  u16* Wkt = (u16*)(w + WSZ);
  u16* Wvt = (u16*)(w + 2 * WSZ);
  u16* Wot = (u16*)(w + 3 * WSZ);
  u16* Qx  = (u16*)(w + 4 * WSZ);
  u16* Kx  = (u16*)(w + 4 * WSZ + XSZ);
  u16* Vx  = (u16*)(w + 4 * WSZ + 2 * XSZ);
  u16* Qp  = (u16*)(w + 4 * WSZ + 3 * XSZ);
  u16* Kp  = (u16*)(w + 4 * WSZ + 4 * XSZ);
  u16* Vt  = (u16*)(w + 4 * WSZ + 5 * XSZ);
  u16* Op  = (u16*)(w + 4 * WSZ + 6 * XSZ);  // total 64 MB

  prep<<<dim3(2048, 1, 7), 256, 0, stream>>>(q, k, v, Wq, Wk, Wv, Wo,
                                             Qx, Kx, Vx, Wqt, Wkt, Wvt, Wot);
  gemm_qkv<<<dim3(8, 32, 3), 256, 0, stream>>>(Qx, Kx, Vx, Wqt, Wkt, Wvt,
                                               bq, bk, bv, Qp, Kp, Vt);
  attn<<<dim3(512), 256, 0, stream>>>(Qp, Kp, Vt, Op);
  gemm_out<<<dim3(8, 64), 256, 0, stream>>>(Op, Wot, bo, (float*)d_out);
}